// Round 10
// baseline (240.714 us; speedup 1.0000x reference)
//
#include <hip/hip_runtime.h>
#include <math.h>

#define B_ 2
#define L_ 2048
#define C_ 768
#define H_ 12
#define D_ 64
#define M_ (B_ * L_)          // 4096
#define MAXLOG 4.605170185988091f   // log(100)

typedef __bf16 bf16;
typedef __bf16 bf16x4 __attribute__((ext_vector_type(4)));
typedef __bf16 bf16x8 __attribute__((ext_vector_type(8)));
typedef float  f32x4  __attribute__((ext_vector_type(4)));

// workspace element counts
#define SZ_  ((size_t)B_ * H_ * L_ * D_)   // 3,145,728 (q,k,vt each)
#define MC_  ((size_t)M_ * C_)             // 3,145,728 (x / ao)
#define WQ_  ((size_t)3 * C_ * C_)         // 1,769,472 (W_qkv)
#define WP_  ((size_t)C_ * C_)             //   589,824 (W_proj)

// ---------------------------------------------------------------------------
// Kernel 0: fused prep (R8 version).
//   seg0: x fp32 -> bf16 (xb)           seg1: W_qkv fp32 -> bf16 (wqb)
//   seg2: W_proj fp32 -> hi/lo bf16     seg3: zero qb..aol (poison insurance)
// ---------------------------------------------------------------------------
__global__ __launch_bounds__(256) void prep(
    const float4* __restrict__ x, const float4* __restrict__ Wq,
    const float4* __restrict__ Wp,
    bf16* __restrict__ xb, bf16* __restrict__ wqb,
    bf16* __restrict__ Wh, bf16* __restrict__ Wl,
    float4* __restrict__ zbase)
{
    const int X4 = (int)(MC_ / 4);         // 786,432
    const int W4 = (int)(WQ_ / 4);         // 442,368
    const int S4 = (int)(WP_ / 4);         // 147,456
    const int Z4 = (int)((3 * SZ_ + 2 * MC_) * sizeof(bf16) / 16);  // 1,966,080
    const int total = X4 + W4 + S4 + Z4;

    const int i0 = blockIdx.x * 256 + threadIdx.x;
    const int stride = gridDim.x * 256;
    for (int i = i0; i < total; i += stride) {
        if (i < X4) {
            const float4 v = x[i];
            bf16x4 o; o[0]=(bf16)v.x; o[1]=(bf16)v.y; o[2]=(bf16)v.z; o[3]=(bf16)v.w;
            *(bf16x4*)&xb[(size_t)i * 4] = o;
        } else if (i < X4 + W4) {
            const int j = i - X4;
            const float4 v = Wq[j];
            bf16x4 o; o[0]=(bf16)v.x; o[1]=(bf16)v.y; o[2]=(bf16)v.z; o[3]=(bf16)v.w;
            *(bf16x4*)&wqb[(size_t)j * 4] = o;
        } else if (i < X4 + W4 + S4) {
            const int j = i - X4 - W4;
            const float4 v = Wp[j];
            bf16x4 h, l;
            h[0]=(bf16)v.x; l[0]=(bf16)(v.x-(float)h[0]);
            h[1]=(bf16)v.y; l[1]=(bf16)(v.y-(float)h[1]);
            h[2]=(bf16)v.z; l[2]=(bf16)(v.z-(float)h[2]);
            h[3]=(bf16)v.w; l[3]=(bf16)(v.w-(float)h[3]);
            *(bf16x4*)&Wh[(size_t)j * 4] = h;
            *(bf16x4*)&Wl[(size_t)j * 4] = l;
        } else {
            zbase[i - X4 - W4 - S4] = (float4){0.f, 0.f, 0.f, 0.f};
        }
    }
}

// ---------------------------------------------------------------------------
// Kernel 1: QKV GEMM, bf16 MFMA, fused l2norm+scale for q/k. (R8 version)
// ---------------------------------------------------------------------------
__global__ __launch_bounds__(256) void qkv_mfma(
    const bf16* __restrict__ A, const bf16* __restrict__ W,
    const float* __restrict__ bias, const float* __restrict__ sml,
    bf16* __restrict__ qb, bf16* __restrict__ kb, bf16* __restrict__ vtb)
{
    __shared__ __align__(16) bf16 As[128][72];
    __shared__ __align__(16) bf16 Bs[64][72];

    const int t    = threadIdx.x;
    const int w    = t >> 6;
    const int lane = t & 63;
    const int quad = lane >> 4;
    const int c    = lane & 15;
    const int m0   = blockIdx.x * 128;
    const int n0   = blockIdx.y * 64;

    f32x4 acc[2][4];
    #pragma unroll
    for (int mt = 0; mt < 2; ++mt)
        #pragma unroll
        for (int nt = 0; nt < 4; ++nt) acc[mt][nt] = (f32x4){0.f,0.f,0.f,0.f};

    for (int kt = 0; kt < C_; kt += 64) {
        __syncthreads();
        #pragma unroll
        for (int p = 0; p < 4; ++p) {
            const int idx = t + p * 256;
            const int row = idx >> 3;
            const int cg  = (idx & 7) * 8;
            *(bf16x8*)&As[row][cg] = *(const bf16x8*)&A[(size_t)(m0 + row) * C_ + kt + cg];
        }
        #pragma unroll
        for (int p = 0; p < 2; ++p) {
            const int idx = t + p * 256;
            const int row = idx >> 3;
            const int cg  = (idx & 7) * 8;
            *(bf16x8*)&Bs[row][cg] = *(const bf16x8*)&W[(size_t)(n0 + row) * C_ + kt + cg];
        }
        __syncthreads();

        #pragma unroll
        for (int ks = 0; ks < 2; ++ks) {
            #pragma unroll
            for (int mt = 0; mt < 2; ++mt) {
                const bf16x8 a = *(const bf16x8*)&As[w * 32 + mt * 16 + c][ks * 32 + quad * 8];
                #pragma unroll
                for (int nt = 0; nt < 4; ++nt) {
                    const bf16x8 b = *(const bf16x8*)&Bs[nt * 16 + c][ks * 32 + quad * 8];
                    acc[mt][nt] = __builtin_amdgcn_mfma_f32_16x16x32_bf16(a, b, acc[mt][nt], 0, 0, 0);
                }
            }
        }
    }

    const int three = blockIdx.y / H_;
    const int h     = blockIdx.y % H_;
    const int bidx  = m0 >> 11;
    const int l0    = (m0 & (L_ - 1)) + w * 32;

    if (three < 2) {
        bf16* dst = (three == 0) ? qb : kb;
        const float scale = (three == 0) ? expf(fminf(sml[h], MAXLOG)) : 1.0f;
        #pragma unroll
        for (int mt = 0; mt < 2; ++mt) {
            float val[4][4];
            float ss[4] = {0.f, 0.f, 0.f, 0.f};
            #pragma unroll
            for (int nt = 0; nt < 4; ++nt) {
                const float bb = bias[n0 + nt * 16 + c];
                #pragma unroll
                for (int reg = 0; reg < 4; ++reg) {
                    const float v = acc[mt][nt][reg] + bb;
                    val[nt][reg] = v;
                    ss[reg] += v * v;
                }
            }
            #pragma unroll
            for (int reg = 0; reg < 4; ++reg) {
                float s = ss[reg];
                #pragma unroll
                for (int off = 1; off < 16; off <<= 1) s += __shfl_xor(s, off, 16);
                const float inv = scale / fmaxf(sqrtf(s), 1e-12f);
                const int l = l0 + mt * 16 + quad * 4 + reg;
                #pragma unroll
                for (int nt = 0; nt < 4; ++nt)
                    dst[((size_t)(bidx * H_ + h) * L_ + l) * D_ + nt * 16 + c] =
                        (bf16)(val[nt][reg] * inv);
            }
        }
    } else {
        #pragma unroll
        for (int mt = 0; mt < 2; ++mt)
            #pragma unroll
            for (int nt = 0; nt < 4; ++nt) {
                const int d = nt * 16 + c;
                const float bb = bias[n0 + d];
                const int l = l0 + mt * 16 + quad * 4;
                bf16x4 o;
                #pragma unroll
                for (int reg = 0; reg < 4; ++reg) o[reg] = (bf16)(acc[mt][nt][reg] + bb);
                *(bf16x4*)&vtb[((size_t)(bidx * H_ + h) * D_ + d) * L_ + l] = o;
            }
    }
}

// ---------------------------------------------------------------------------
// Kernel 2: flash attention v4, bf16 MFMA, fixed-offset softmax.
//   BQ=128: wave owns 32 Q-rows (2 m-tiles), K/V b-frags shared across them
//   -> LDS reads per unit work halved vs R8. Q a-frags hoisted to registers;
//   P overlays the Q LDS buffer. NO K-split: full L per block, normalized
//   bf16 hi/lo epilogue (R8 format) -> no fp32 partial round-trip, no write
//   amplification. Grid (16, 24) = 384 blocks (~1.5/CU; loaded CUs carry
//   ~2x24 us of LDS work, still below R8's 57 us/CU).
// ---------------------------------------------------------------------------
__global__ __launch_bounds__(256) void flash_mfma(
    const bf16* __restrict__ q, const bf16* __restrict__ k,
    const bf16* __restrict__ vt, const float* __restrict__ bias,
    const float* __restrict__ sml,
    bf16* __restrict__ aoh, bf16* __restrict__ aol)
{
    __shared__ __align__(16) bf16 QPs[128][72];   // Q in prologue, then P
    __shared__ __align__(16) bf16 Ks [64][72];
    __shared__ __align__(16) bf16 Vts[64][72];

    const int t    = threadIdx.x;
    const int w    = t >> 6;
    const int lane = t & 63;
    const int quad = lane >> 4;
    const int c    = lane & 15;
    const int q0   = blockIdx.x * 128;
    const int bh   = blockIdx.y;
    const int h    = bh % H_;
    const int b    = bh / H_;
    const size_t base  = (size_t)bh * L_ * D_;
    const size_t vbase = (size_t)bh * D_ * L_;

    const float FMAX = expf(fminf(sml[h], MAXLOG)) + 8.0f;

    // ---- prologue: stage Q tile, hoist a-frags, free QPs for P ----
    #pragma unroll
    for (int p = 0; p < 4; ++p) {
        const int f = t + p * 256;
        const int r = f >> 3, d0 = (f & 7) * 8;
        *(bf16x8*)&QPs[r][d0] = *(const bf16x8*)&q[base + (size_t)(q0 + r) * D_ + d0];
    }
    __syncthreads();
    bf16x8 Qreg[2][2];
    #pragma unroll
    for (int mt = 0; mt < 2; ++mt)
        #pragma unroll
        for (int ks = 0; ks < 2; ++ks)
            Qreg[mt][ks] = *(const bf16x8*)&QPs[w * 32 + mt * 16 + c][ks * 32 + quad * 8];
    __syncthreads();   // all Q reads done before first P write

    float l_acc[2][4] = {};
    f32x4 O[2][4];
    #pragma unroll
    for (int mt = 0; mt < 2; ++mt)
        #pragma unroll
        for (int nt = 0; nt < 4; ++nt) O[mt][nt] = (f32x4){0.f, 0.f, 0.f, 0.f};

    for (int kt = 0; kt < L_; kt += 64) {
        __syncthreads();   // prev iter's Ks/Vts/P reads complete
        #pragma unroll
        for (int p = 0; p < 2; ++p) {
            const int f = t + p * 256;
            const int r = f >> 3, c0 = (f & 7) * 8;
            *(bf16x8*)&Ks [r][c0] = *(const bf16x8*)&k [base  + (size_t)(kt + r) * D_ + c0];
            *(bf16x8*)&Vts[r][c0] = *(const bf16x8*)&vt[vbase + (size_t)r * L_ + kt + c0];
        }

        // S init from the bias tile (loads drain at the same barrier as staging)
        f32x4 S[2][4];
        #pragma unroll
        for (int mt = 0; mt < 2; ++mt) {
            const int rb = q0 + w * 32 + mt * 16 + quad * 4;
            #pragma unroll
            for (int nt = 0; nt < 4; ++nt)
                #pragma unroll
                for (int reg = 0; reg < 4; ++reg)
                    S[mt][nt][reg] = bias[(size_t)(rb + reg) * L_ + kt + nt * 16 + c];
        }
        __syncthreads();

        // ---- S = bias + Q K^T (b-frags shared across the 2 m-tiles) ----
        #pragma unroll
        for (int ks = 0; ks < 2; ++ks) {
            bf16x8 bb[4];
            #pragma unroll
            for (int nt = 0; nt < 4; ++nt)
                bb[nt] = *(const bf16x8*)&Ks[nt * 16 + c][ks * 32 + quad * 8];
            #pragma unroll
            for (int mt = 0; mt < 2; ++mt)
                #pragma unroll
                for (int nt = 0; nt < 4; ++nt)
                    S[mt][nt] = __builtin_amdgcn_mfma_f32_16x16x32_bf16(
                        Qreg[mt][ks], bb[nt], S[mt][nt], 0, 0, 0);
        }

        // ---- p = exp(s - FMAX); per-lane row-sum; P -> LDS (over QPs) ----
        #pragma unroll
        for (int mt = 0; mt < 2; ++mt)
            #pragma unroll
            for (int nt = 0; nt < 4; ++nt)
                #pragma unroll
                for (int reg = 0; reg < 4; ++reg) {
                    const float pv = __expf(S[mt][nt][reg] - FMAX);
                    l_acc[mt][reg] += pv;
                    QPs[w * 32 + mt * 16 + quad * 4 + reg][nt * 16 + c] = (bf16)pv;
                }
        __syncthreads();

        // ---- O += P V ----
        #pragma unroll
        for (int ks = 0; ks < 2; ++ks) {
            bf16x8 bb[4];
            #pragma unroll
            for (int nt = 0; nt < 4; ++nt)
                bb[nt] = *(const bf16x8*)&Vts[nt * 16 + c][ks * 32 + quad * 8];
            #pragma unroll
            for (int mt = 0; mt < 2; ++mt) {
                const bf16x8 a = *(const bf16x8*)&QPs[w * 32 + mt * 16 + c][ks * 32 + quad * 8];
                #pragma unroll
                for (int nt = 0; nt < 4; ++nt)
                    O[mt][nt] = __builtin_amdgcn_mfma_f32_16x16x32_bf16(
                        a, bb[nt], O[mt][nt], 0, 0, 0);
            }
        }
    }

    // ---- epilogue: reduce row-sums, normalized hi/lo bf16 output ----
    #pragma unroll
    for (int mt = 0; mt < 2; ++mt)
        #pragma unroll
        for (int reg = 0; reg < 4; ++reg) {
            float rs = l_acc[mt][reg];
            #pragma unroll
            for (int off = 1; off < 16; off <<= 1) rs += __shfl_xor(rs, off, 16);
            const float linv = 1.0f / rs;
            const int   row  = q0 + w * 32 + mt * 16 + quad * 4 + reg;
            const size_t o   = ((size_t)(b * L_ + row)) * C_ + h * 64 + c;
            #pragma unroll
            for (int nt = 0; nt < 4; ++nt) {
                const float v  = O[mt][nt][reg] * linv;
                const bf16  hv = (bf16)v;
                aoh[o + nt * 16] = hv;
                aol[o + nt * 16] = (bf16)(v - (float)hv);
            }
        }
}

// ---------------------------------------------------------------------------
// Kernel 3: projection GEMM, hi/lo-split bf16 MFMA, pre-split inputs. (R8)
// ---------------------------------------------------------------------------
__global__ __launch_bounds__(256) void proj_mfma(
    const bf16* __restrict__ Ahg, const bf16* __restrict__ Alg,
    const bf16* __restrict__ Whg, const bf16* __restrict__ Wlg,
    const float* __restrict__ bias, float* __restrict__ outp)
{
    __shared__ __align__(16) bf16 Ah[128][72];
    __shared__ __align__(16) bf16 Al[128][72];
    __shared__ __align__(16) bf16 Bh[64][72];
    __shared__ __align__(16) bf16 Bl[64][72];

    const int t    = threadIdx.x;
    const int w    = t >> 6;
    const int lane = t & 63;
    const int quad = lane >> 4;
    const int c    = lane & 15;
    const int m0   = blockIdx.x * 128;
    const int n0   = blockIdx.y * 64;

    f32x4 acc[2][4];
    #pragma unroll
    for (int mt = 0; mt < 2; ++mt)
        #pragma unroll
        for (int nt = 0; nt < 4; ++nt) acc[mt][nt] = (f32x4){0.f,0.f,0.f,0.f};

    for (int kt = 0; kt < C_; kt += 64) {
        __syncthreads();
        #pragma unroll
        for (int p = 0; p < 4; ++p) {
            const int idx = t + p * 256;
            const int row = idx >> 3;
            const int cg  = (idx & 7) * 8;
            *(bf16x8*)&Ah[row][cg] = *(const bf16x8*)&Ahg[(size_t)(m0 + row) * C_ + kt + cg];
            *(bf16x8*)&Al[row][cg] = *(const bf16x8*)&Alg[(size_t)(m0 + row) * C_ + kt + cg];
        }
        #pragma unroll
        for (int p = 0; p < 2; ++p) {
            const int idx = t + p * 256;
            const int row = idx >> 3;
            const int cg  = (idx & 7) * 8;
            *(bf16x8*)&Bh[row][cg] = *(const bf16x8*)&Whg[(size_t)(n0 + row) * C_ + kt + cg];
            *(bf16x8*)&Bl[row][cg] = *(const bf16x8*)&Wlg[(size_t)(n0 + row) * C_ + kt + cg];
        }
        __syncthreads();

        #pragma unroll
        for (int ks = 0; ks < 2; ++ks) {
            #pragma unroll
            for (int mt = 0; mt < 2; ++mt) {
                const bf16x8 ah = *(const bf16x8*)&Ah[w * 32 + mt * 16 + c][ks * 32 + quad * 8];
                const bf16x8 al = *(const bf16x8*)&Al[w * 32 + mt * 16 + c][ks * 32 + quad * 8];
                #pragma unroll
                for (int nt = 0; nt < 4; ++nt) {
                    const bf16x8 bh = *(const bf16x8*)&Bh[nt * 16 + c][ks * 32 + quad * 8];
                    const bf16x8 bl = *(const bf16x8*)&Bl[nt * 16 + c][ks * 32 + quad * 8];
                    acc[mt][nt] = __builtin_amdgcn_mfma_f32_16x16x32_bf16(ah, bh, acc[mt][nt], 0, 0, 0);
                    acc[mt][nt] = __builtin_amdgcn_mfma_f32_16x16x32_bf16(ah, bl, acc[mt][nt], 0, 0, 0);
                    acc[mt][nt] = __builtin_amdgcn_mfma_f32_16x16x32_bf16(al, bh, acc[mt][nt], 0, 0, 0);
                }
            }
        }
    }

    #pragma unroll
    for (int mt = 0; mt < 2; ++mt)
        #pragma unroll
        for (int nt = 0; nt < 4; ++nt) {
            const int col = n0 + nt * 16 + c;
            const float bb = bias[col];
            #pragma unroll
            for (int reg = 0; reg < 4; ++reg) {
                const int row = m0 + w * 32 + mt * 16 + quad * 4 + reg;
                outp[(size_t)row * C_ + col] = acc[mt][nt][reg] + bb;
            }
        }
}

// ---------------------------------------------------------------------------
extern "C" void kernel_launch(void* const* d_in, const int* in_sizes, int n_in,
                              void* d_out, int out_size, void* d_ws, size_t ws_size,
                              hipStream_t stream)
{
    const float* x         = (const float*)d_in[0];
    const float* attn_bias = (const float*)d_in[1];
    const float* W_qkv     = (const float*)d_in[2];
    const float* b_qkv     = (const float*)d_in[3];
    const float* sml       = (const float*)d_in[4];
    const float* W_proj    = (const float*)d_in[5];
    const float* b_proj    = (const float*)d_in[6];
    float* out = (float*)d_out;

    // ws layout (bf16 elements): qb,kb,vtb | aoh,aol | Wh,Wl | xb | wqb
    bf16* qb  = (bf16*)d_ws;
    bf16* kb  = qb  + SZ_;
    bf16* vtb = kb  + SZ_;
    bf16* aoh = vtb + SZ_;
    bf16* aol = aoh + MC_;
    bf16* Wh  = aol + MC_;
    bf16* Wl  = Wh  + WP_;
    bf16* xb  = Wl  + WP_;
    bf16* wqb = xb  + MC_;

    // 0) fused prep: cvt x/W_qkv to bf16, split W_proj, zero qb..aol
    prep<<<2048, 256, 0, stream>>>(
        (const float4*)x, (const float4*)W_qkv, (const float4*)W_proj,
        xb, wqb, Wh, Wl, (float4*)qb);

    // 1) QKV GEMM (bf16 MFMA, fused l2norm+scale) -> q,k [B,H,L,D]; v^T [B,H,D,L]
    qkv_mfma<<<dim3(M_ / 128, (3 * C_) / 64), 256, 0, stream>>>(
        xb, wqb, b_qkv, sml, qb, kb, vtb);

    // 2) flash attention v4 (BQ=128, no K-split) -> aoh/aol [B,L,C]
    flash_mfma<<<dim3(L_ / 128, B_ * H_), 256, 0, stream>>>(
        qb, kb, vtb, attn_bias, sml, aoh, aol);

    // 3) projection GEMM (hi/lo split MFMA, fp32-grade)
    proj_mfma<<<dim3(M_ / 128, C_ / 64), 256, 0, stream>>>(
        aoh, aol, Wh, Wl, b_proj, out);
}

// Round 11
// 209.360 us; speedup vs baseline: 1.1498x; 1.1498x over previous
//
#include <hip/hip_runtime.h>
#include <math.h>

#define B_ 2
#define L_ 2048
#define C_ 768
#define H_ 12
#define D_ 64
#define M_ (B_ * L_)          // 4096
#define MAXLOG 4.605170185988091f   // log(100)

typedef __bf16 bf16;
typedef __bf16 bf16x4 __attribute__((ext_vector_type(4)));
typedef __bf16 bf16x8 __attribute__((ext_vector_type(8)));
typedef float  f32x4  __attribute__((ext_vector_type(4)));

// workspace element counts
#define SZ_  ((size_t)B_ * H_ * L_ * D_)   // 3,145,728 (q,k,vt each)
#define MC_  ((size_t)M_ * C_)             // 3,145,728 (x / ao)
#define WQ_  ((size_t)3 * C_ * C_)         // 1,769,472 (W_qkv)
#define WP_  ((size_t)C_ * C_)             //   589,824 (W_proj)

// ---------------------------------------------------------------------------
// Kernel 0: fused prep (R8 version).
// ---------------------------------------------------------------------------
__global__ __launch_bounds__(256) void prep(
    const float4* __restrict__ x, const float4* __restrict__ Wq,
    const float4* __restrict__ Wp,
    bf16* __restrict__ xb, bf16* __restrict__ wqb,
    bf16* __restrict__ Wh, bf16* __restrict__ Wl,
    float4* __restrict__ zbase)
{
    const int X4 = (int)(MC_ / 4);
    const int W4 = (int)(WQ_ / 4);
    const int S4 = (int)(WP_ / 4);
    const int Z4 = (int)((3 * SZ_ + 2 * MC_) * sizeof(bf16) / 16);
    const int total = X4 + W4 + S4 + Z4;

    const int i0 = blockIdx.x * 256 + threadIdx.x;
    const int stride = gridDim.x * 256;
    for (int i = i0; i < total; i += stride) {
        if (i < X4) {
            const float4 v = x[i];
            bf16x4 o; o[0]=(bf16)v.x; o[1]=(bf16)v.y; o[2]=(bf16)v.z; o[3]=(bf16)v.w;
            *(bf16x4*)&xb[(size_t)i * 4] = o;
        } else if (i < X4 + W4) {
            const int j = i - X4;
            const float4 v = Wq[j];
            bf16x4 o; o[0]=(bf16)v.x; o[1]=(bf16)v.y; o[2]=(bf16)v.z; o[3]=(bf16)v.w;
            *(bf16x4*)&wqb[(size_t)j * 4] = o;
        } else if (i < X4 + W4 + S4) {
            const int j = i - X4 - W4;
            const float4 v = Wp[j];
            bf16x4 h, l;
            h[0]=(bf16)v.x; l[0]=(bf16)(v.x-(float)h[0]);
            h[1]=(bf16)v.y; l[1]=(bf16)(v.y-(float)h[1]);
            h[2]=(bf16)v.z; l[2]=(bf16)(v.z-(float)h[2]);
            h[3]=(bf16)v.w; l[3]=(bf16)(v.w-(float)h[3]);
            *(bf16x4*)&Wh[(size_t)j * 4] = h;
            *(bf16x4*)&Wl[(size_t)j * 4] = l;
        } else {
            zbase[i - X4 - W4 - S4] = (float4){0.f, 0.f, 0.f, 0.f};
        }
    }
}

// ---------------------------------------------------------------------------
// Kernel 1: QKV GEMM, bf16 MFMA, fused l2norm+scale for q/k. (R8 version)
// ---------------------------------------------------------------------------
__global__ __launch_bounds__(256) void qkv_mfma(
    const bf16* __restrict__ A, const bf16* __restrict__ W,
    const float* __restrict__ bias, const float* __restrict__ sml,
    bf16* __restrict__ qb, bf16* __restrict__ kb, bf16* __restrict__ vtb)
{
    __shared__ __align__(16) bf16 As[128][72];
    __shared__ __align__(16) bf16 Bs[64][72];

    const int t    = threadIdx.x;
    const int w    = t >> 6;
    const int lane = t & 63;
    const int quad = lane >> 4;
    const int c    = lane & 15;
    const int m0   = blockIdx.x * 128;
    const int n0   = blockIdx.y * 64;

    f32x4 acc[2][4];
    #pragma unroll
    for (int mt = 0; mt < 2; ++mt)
        #pragma unroll
        for (int nt = 0; nt < 4; ++nt) acc[mt][nt] = (f32x4){0.f,0.f,0.f,0.f};

    for (int kt = 0; kt < C_; kt += 64) {
        __syncthreads();
        #pragma unroll
        for (int p = 0; p < 4; ++p) {
            const int idx = t + p * 256;
            const int row = idx >> 3;
            const int cg  = (idx & 7) * 8;
            *(bf16x8*)&As[row][cg] = *(const bf16x8*)&A[(size_t)(m0 + row) * C_ + kt + cg];
        }
        #pragma unroll
        for (int p = 0; p < 2; ++p) {
            const int idx = t + p * 256;
            const int row = idx >> 3;
            const int cg  = (idx & 7) * 8;
            *(bf16x8*)&Bs[row][cg] = *(const bf16x8*)&W[(size_t)(n0 + row) * C_ + kt + cg];
        }
        __syncthreads();

        #pragma unroll
        for (int ks = 0; ks < 2; ++ks) {
            #pragma unroll
            for (int mt = 0; mt < 2; ++mt) {
                const bf16x8 a = *(const bf16x8*)&As[w * 32 + mt * 16 + c][ks * 32 + quad * 8];
                #pragma unroll
                for (int nt = 0; nt < 4; ++nt) {
                    const bf16x8 b = *(const bf16x8*)&Bs[nt * 16 + c][ks * 32 + quad * 8];
                    acc[mt][nt] = __builtin_amdgcn_mfma_f32_16x16x32_bf16(a, b, acc[mt][nt], 0, 0, 0);
                }
            }
        }
    }

    const int three = blockIdx.y / H_;
    const int h     = blockIdx.y % H_;
    const int bidx  = m0 >> 11;
    const int l0    = (m0 & (L_ - 1)) + w * 32;

    if (three < 2) {
        bf16* dst = (three == 0) ? qb : kb;
        const float scale = (three == 0) ? expf(fminf(sml[h], MAXLOG)) : 1.0f;
        #pragma unroll
        for (int mt = 0; mt < 2; ++mt) {
            float val[4][4];
            float ss[4] = {0.f, 0.f, 0.f, 0.f};
            #pragma unroll
            for (int nt = 0; nt < 4; ++nt) {
                const float bb = bias[n0 + nt * 16 + c];
                #pragma unroll
                for (int reg = 0; reg < 4; ++reg) {
                    const float v = acc[mt][nt][reg] + bb;
                    val[nt][reg] = v;
                    ss[reg] += v * v;
                }
            }
            #pragma unroll
            for (int reg = 0; reg < 4; ++reg) {
                float s = ss[reg];
                #pragma unroll
                for (int off = 1; off < 16; off <<= 1) s += __shfl_xor(s, off, 16);
                const float inv = scale / fmaxf(sqrtf(s), 1e-12f);
                const int l = l0 + mt * 16 + quad * 4 + reg;
                #pragma unroll
                for (int nt = 0; nt < 4; ++nt)
                    dst[((size_t)(bidx * H_ + h) * L_ + l) * D_ + nt * 16 + c] =
                        (bf16)(val[nt][reg] * inv);
            }
        }
    } else {
        #pragma unroll
        for (int mt = 0; mt < 2; ++mt)
            #pragma unroll
            for (int nt = 0; nt < 4; ++nt) {
                const int d = nt * 16 + c;
                const float bb = bias[n0 + d];
                const int l = l0 + mt * 16 + quad * 4;
                bf16x4 o;
                #pragma unroll
                for (int reg = 0; reg < 4; ++reg) o[reg] = (bf16)(acc[mt][nt][reg] + bb);
                *(bf16x4*)&vtb[((size_t)(bidx * H_ + h) * D_ + d) * L_ + l] = o;
            }
    }
}

// ---------------------------------------------------------------------------
// Kernel 2: flash attention v5 = R8 structure (BQ=64, 768 blocks, 3/CU)
//   + REGISTER PREFETCH one iteration ahead: K/V chunks (4x bf16x8) and the
//     bias tile (16 floats) are loaded during iter i-1's compute phase, so
//     the vmcnt drain at barrier-2 is ~free (cp.async-style pipeline).
//   + Q a-frags hoisted to registers; P overlays the Q LDS buffer.
// ---------------------------------------------------------------------------
__global__ __launch_bounds__(256) void flash_mfma(
    const bf16* __restrict__ q, const bf16* __restrict__ k,
    const bf16* __restrict__ vt, const float* __restrict__ bias,
    const float* __restrict__ sml,
    bf16* __restrict__ aoh, bf16* __restrict__ aol)
{
    __shared__ __align__(16) bf16 QPs[64][72];   // Q in prologue, then P
    __shared__ __align__(16) bf16 Ks [64][72];
    __shared__ __align__(16) bf16 Vts[64][72];

    const int t    = threadIdx.x;
    const int w    = t >> 6;
    const int lane = t & 63;
    const int quad = lane >> 4;
    const int c    = lane & 15;
    const int q0   = blockIdx.x * 64;
    const int bh   = blockIdx.y;
    const int h    = bh % H_;
    const int b    = bh / H_;
    const size_t base  = (size_t)bh * L_ * D_;
    const size_t vbase = (size_t)bh * D_ * L_;

    const float FMAX = expf(fminf(sml[h], MAXLOG)) + 8.0f;

    // ---- prologue: stage Q, hoist a-frags (QPs then freed for P) ----
    #pragma unroll
    for (int p = 0; p < 2; ++p) {
        const int f = t + p * 256;
        const int r = f >> 3, d0 = (f & 7) * 8;
        *(bf16x8*)&QPs[r][d0] = *(const bf16x8*)&q[base + (size_t)(q0 + r) * D_ + d0];
    }
    __syncthreads();
    bf16x8 Qreg[2];
    Qreg[0] = *(const bf16x8*)&QPs[w * 16 + c][quad * 8];
    Qreg[1] = *(const bf16x8*)&QPs[w * 16 + c][32 + quad * 8];

    const int rbase = q0 + w * 16 + quad * 4;

    // per-thread staging chunk coordinates (fixed across iters)
    const int r0  = t >> 3,        c00 = (t & 7) * 8;
    const int r1  = (t + 256) >> 3, c01 = ((t + 256) & 7) * 8;

    // ---- prefetch iteration 0 ----
    bf16x8 kreg[2], vreg[2];
    float  breg[4][4];
    kreg[0] = *(const bf16x8*)&k [base  + (size_t)r0 * D_ + c00];
    kreg[1] = *(const bf16x8*)&k [base  + (size_t)r1 * D_ + c01];
    vreg[0] = *(const bf16x8*)&vt[vbase + (size_t)r0 * L_ + c00];
    vreg[1] = *(const bf16x8*)&vt[vbase + (size_t)r1 * L_ + c01];
    #pragma unroll
    for (int tile = 0; tile < 4; ++tile)
        #pragma unroll
        for (int reg = 0; reg < 4; ++reg)
            breg[tile][reg] = bias[(size_t)(rbase + reg) * L_ + tile * 16 + c];

    float l_acc[4] = {0.f, 0.f, 0.f, 0.f};
    f32x4 O[4];
    #pragma unroll
    for (int i = 0; i < 4; ++i) O[i] = (f32x4){0.f, 0.f, 0.f, 0.f};

    for (int kt = 0; kt < L_; kt += 64) {
        __syncthreads();   // prev iter's Ks/Vts/P reads complete (also gates Q-hoist)

        // write the prefetched K/V tile to LDS
        *(bf16x8*)&Ks [r0][c00] = kreg[0];
        *(bf16x8*)&Ks [r1][c01] = kreg[1];
        *(bf16x8*)&Vts[r0][c00] = vreg[0];
        *(bf16x8*)&Vts[r1][c01] = vreg[1];

        // S accumulator from the prefetched bias tile
        f32x4 S[4];
        #pragma unroll
        for (int tile = 0; tile < 4; ++tile)
            #pragma unroll
            for (int reg = 0; reg < 4; ++reg)
                S[tile][reg] = breg[tile][reg];

        // issue next iteration's loads — they complete during this compute
        const int kt2 = kt + 64;
        if (kt2 < L_) {
            kreg[0] = *(const bf16x8*)&k [base  + (size_t)(kt2 + r0) * D_ + c00];
            kreg[1] = *(const bf16x8*)&k [base  + (size_t)(kt2 + r1) * D_ + c01];
            vreg[0] = *(const bf16x8*)&vt[vbase + (size_t)r0 * L_ + kt2 + c00];
            vreg[1] = *(const bf16x8*)&vt[vbase + (size_t)r1 * L_ + kt2 + c01];
            #pragma unroll
            for (int tile = 0; tile < 4; ++tile)
                #pragma unroll
                for (int reg = 0; reg < 4; ++reg)
                    breg[tile][reg] = bias[(size_t)(rbase + reg) * L_ + kt2 + tile * 16 + c];
        }
        __syncthreads();   // staging visible

        // ---- S = bias + Q K^T ----
        #pragma unroll
        for (int ks = 0; ks < 2; ++ks) {
            #pragma unroll
            for (int tile = 0; tile < 4; ++tile) {
                const bf16x8 bb = *(const bf16x8*)&Ks[tile * 16 + c][ks * 32 + quad * 8];
                S[tile] = __builtin_amdgcn_mfma_f32_16x16x32_bf16(Qreg[ks], bb, S[tile], 0, 0, 0);
            }
        }

        // ---- p = exp(s - FMAX); per-lane row-sum; P -> LDS (over QPs) ----
        #pragma unroll
        for (int tile = 0; tile < 4; ++tile)
            #pragma unroll
            for (int reg = 0; reg < 4; ++reg) {
                const float pv = __expf(S[tile][reg] - FMAX);
                l_acc[reg] += pv;
                QPs[w * 16 + quad * 4 + reg][tile * 16 + c] = (bf16)pv;
            }
        __syncthreads();

        // ---- O += P V ----
        #pragma unroll
        for (int ks = 0; ks < 2; ++ks) {
            const bf16x8 a = *(const bf16x8*)&QPs[w * 16 + c][ks * 32 + quad * 8];
            #pragma unroll
            for (int tile = 0; tile < 4; ++tile) {
                const bf16x8 bb = *(const bf16x8*)&Vts[tile * 16 + c][ks * 32 + quad * 8];
                O[tile] = __builtin_amdgcn_mfma_f32_16x16x32_bf16(a, bb, O[tile], 0, 0, 0);
            }
        }
    }

    // ---- epilogue: reduce row-sums, normalized hi/lo bf16 output ----
    #pragma unroll
    for (int reg = 0; reg < 4; ++reg) {
        float rs = l_acc[reg];
        #pragma unroll
        for (int off = 1; off < 16; off <<= 1) rs += __shfl_xor(rs, off, 16);
        const float linv = 1.0f / rs;
        const int   row  = q0 + w * 16 + quad * 4 + reg;
        const size_t o   = ((size_t)(b * L_ + row)) * C_ + h * 64 + c;
        #pragma unroll
        for (int tile = 0; tile < 4; ++tile) {
            const float v  = O[tile][reg] * linv;
            const bf16  hv = (bf16)v;
            aoh[o + tile * 16] = hv;
            aol[o + tile * 16] = (bf16)(v - (float)hv);
        }
    }
}

// ---------------------------------------------------------------------------
// Kernel 3: projection GEMM, hi/lo-split bf16 MFMA, pre-split inputs. (R8)
// ---------------------------------------------------------------------------
__global__ __launch_bounds__(256) void proj_mfma(
    const bf16* __restrict__ Ahg, const bf16* __restrict__ Alg,
    const bf16* __restrict__ Whg, const bf16* __restrict__ Wlg,
    const float* __restrict__ bias, float* __restrict__ outp)
{
    __shared__ __align__(16) bf16 Ah[128][72];
    __shared__ __align__(16) bf16 Al[128][72];
    __shared__ __align__(16) bf16 Bh[64][72];
    __shared__ __align__(16) bf16 Bl[64][72];

    const int t    = threadIdx.x;
    const int w    = t >> 6;
    const int lane = t & 63;
    const int quad = lane >> 4;
    const int c    = lane & 15;
    const int m0   = blockIdx.x * 128;
    const int n0   = blockIdx.y * 64;

    f32x4 acc[2][4];
    #pragma unroll
    for (int mt = 0; mt < 2; ++mt)
        #pragma unroll
        for (int nt = 0; nt < 4; ++nt) acc[mt][nt] = (f32x4){0.f,0.f,0.f,0.f};

    for (int kt = 0; kt < C_; kt += 64) {
        __syncthreads();
        #pragma unroll
        for (int p = 0; p < 4; ++p) {
            const int idx = t + p * 256;
            const int row = idx >> 3;
            const int cg  = (idx & 7) * 8;
            *(bf16x8*)&Ah[row][cg] = *(const bf16x8*)&Ahg[(size_t)(m0 + row) * C_ + kt + cg];
            *(bf16x8*)&Al[row][cg] = *(const bf16x8*)&Alg[(size_t)(m0 + row) * C_ + kt + cg];
        }
        #pragma unroll
        for (int p = 0; p < 2; ++p) {
            const int idx = t + p * 256;
            const int row = idx >> 3;
            const int cg  = (idx & 7) * 8;
            *(bf16x8*)&Bh[row][cg] = *(const bf16x8*)&Whg[(size_t)(n0 + row) * C_ + kt + cg];
            *(bf16x8*)&Bl[row][cg] = *(const bf16x8*)&Wlg[(size_t)(n0 + row) * C_ + kt + cg];
        }
        __syncthreads();

        #pragma unroll
        for (int ks = 0; ks < 2; ++ks) {
            #pragma unroll
            for (int mt = 0; mt < 2; ++mt) {
                const bf16x8 ah = *(const bf16x8*)&Ah[w * 32 + mt * 16 + c][ks * 32 + quad * 8];
                const bf16x8 al = *(const bf16x8*)&Al[w * 32 + mt * 16 + c][ks * 32 + quad * 8];
                #pragma unroll
                for (int nt = 0; nt < 4; ++nt) {
                    const bf16x8 bh = *(const bf16x8*)&Bh[nt * 16 + c][ks * 32 + quad * 8];
                    const bf16x8 bl = *(const bf16x8*)&Bl[nt * 16 + c][ks * 32 + quad * 8];
                    acc[mt][nt] = __builtin_amdgcn_mfma_f32_16x16x32_bf16(ah, bh, acc[mt][nt], 0, 0, 0);
                    acc[mt][nt] = __builtin_amdgcn_mfma_f32_16x16x32_bf16(ah, bl, acc[mt][nt], 0, 0, 0);
                    acc[mt][nt] = __builtin_amdgcn_mfma_f32_16x16x32_bf16(al, bh, acc[mt][nt], 0, 0, 0);
                }
            }
        }
    }

    #pragma unroll
    for (int mt = 0; mt < 2; ++mt)
        #pragma unroll
        for (int nt = 0; nt < 4; ++nt) {
            const int col = n0 + nt * 16 + c;
            const float bb = bias[col];
            #pragma unroll
            for (int reg = 0; reg < 4; ++reg) {
                const int row = m0 + w * 32 + mt * 16 + quad * 4 + reg;
                outp[(size_t)row * C_ + col] = acc[mt][nt][reg] + bb;
            }
        }
}

// ---------------------------------------------------------------------------
extern "C" void kernel_launch(void* const* d_in, const int* in_sizes, int n_in,
                              void* d_out, int out_size, void* d_ws, size_t ws_size,
                              hipStream_t stream)
{
    const float* x         = (const float*)d_in[0];
    const float* attn_bias = (const float*)d_in[1];
    const float* W_qkv     = (const float*)d_in[2];
    const float* b_qkv     = (const float*)d_in[3];
    const float* sml       = (const float*)d_in[4];
    const float* W_proj    = (const float*)d_in[5];
    const float* b_proj    = (const float*)d_in[6];
    float* out = (float*)d_out;

    // ws layout (bf16 elements): qb,kb,vtb | aoh,aol | Wh,Wl | xb | wqb
    bf16* qb  = (bf16*)d_ws;
    bf16* kb  = qb  + SZ_;
    bf16* vtb = kb  + SZ_;
    bf16* aoh = vtb + SZ_;
    bf16* aol = aoh + MC_;
    bf16* Wh  = aol + MC_;
    bf16* Wl  = Wh  + WP_;
    bf16* xb  = Wl  + WP_;
    bf16* wqb = xb  + MC_;

    // 0) fused prep: cvt x/W_qkv to bf16, split W_proj, zero qb..aol
    prep<<<2048, 256, 0, stream>>>(
        (const float4*)x, (const float4*)W_qkv, (const float4*)W_proj,
        xb, wqb, Wh, Wl, (float4*)qb);

    // 1) QKV GEMM (bf16 MFMA, fused l2norm+scale)
    qkv_mfma<<<dim3(M_ / 128, (3 * C_) / 64), 256, 0, stream>>>(
        xb, wqb, b_qkv, sml, qb, kb, vtb);

    // 2) flash attention v5 (BQ=64, 768 blocks, register prefetch)
    flash_mfma<<<dim3(L_ / 64, B_ * H_), 256, 0, stream>>>(
        qb, kb, vtb, attn_bias, sml, aoh, aol);

    // 3) projection GEMM (hi/lo split MFMA, fp32-grade)
    proj_mfma<<<dim3(M_ / 128, C_ / 64), 256, 0, stream>>>(
        aoh, aol, Wh, Wl, b_proj, out);
}

// Round 12
// 206.214 us; speedup vs baseline: 1.1673x; 1.0153x over previous
//
#include <hip/hip_runtime.h>
#include <math.h>

#define B_ 2
#define L_ 2048
#define C_ 768
#define H_ 12
#define D_ 64
#define M_ (B_ * L_)          // 4096
#define MAXLOG 4.605170185988091f   // log(100)

typedef __bf16 bf16;
typedef __bf16 bf16x4 __attribute__((ext_vector_type(4)));
typedef __bf16 bf16x8 __attribute__((ext_vector_type(8)));
typedef float  f32x4  __attribute__((ext_vector_type(4)));

// workspace element counts
#define SZ_  ((size_t)B_ * H_ * L_ * D_)   // 3,145,728 (q,k,vt each)
#define MC_  ((size_t)M_ * C_)             // 3,145,728 (x / ao)
#define WQ_  ((size_t)3 * C_ * C_)         // 1,769,472 (W_qkv)
#define WP_  ((size_t)C_ * C_)             //   589,824 (W_proj)

// ---------------------------------------------------------------------------
// Kernel 0: fused prep (unchanged R8).
// ---------------------------------------------------------------------------
__global__ __launch_bounds__(256) void prep(
    const float4* __restrict__ x, const float4* __restrict__ Wq,
    const float4* __restrict__ Wp,
    bf16* __restrict__ xb, bf16* __restrict__ wqb,
    bf16* __restrict__ Wh, bf16* __restrict__ Wl,
    float4* __restrict__ zbase)
{
    const int X4 = (int)(MC_ / 4);
    const int W4 = (int)(WQ_ / 4);
    const int S4 = (int)(WP_ / 4);
    const int Z4 = (int)((3 * SZ_ + 2 * MC_) * sizeof(bf16) / 16);
    const int total = X4 + W4 + S4 + Z4;

    const int i0 = blockIdx.x * 256 + threadIdx.x;
    const int stride = gridDim.x * 256;
    for (int i = i0; i < total; i += stride) {
        if (i < X4) {
            const float4 v = x[i];
            bf16x4 o; o[0]=(bf16)v.x; o[1]=(bf16)v.y; o[2]=(bf16)v.z; o[3]=(bf16)v.w;
            *(bf16x4*)&xb[(size_t)i * 4] = o;
        } else if (i < X4 + W4) {
            const int j = i - X4;
            const float4 v = Wq[j];
            bf16x4 o; o[0]=(bf16)v.x; o[1]=(bf16)v.y; o[2]=(bf16)v.z; o[3]=(bf16)v.w;
            *(bf16x4*)&wqb[(size_t)j * 4] = o;
        } else if (i < X4 + W4 + S4) {
            const int j = i - X4 - W4;
            const float4 v = Wp[j];
            bf16x4 h, l;
            h[0]=(bf16)v.x; l[0]=(bf16)(v.x-(float)h[0]);
            h[1]=(bf16)v.y; l[1]=(bf16)(v.y-(float)h[1]);
            h[2]=(bf16)v.z; l[2]=(bf16)(v.z-(float)h[2]);
            h[3]=(bf16)v.w; l[3]=(bf16)(v.w-(float)h[3]);
            *(bf16x4*)&Wh[(size_t)j * 4] = h;
            *(bf16x4*)&Wl[(size_t)j * 4] = l;
        } else {
            zbase[i - X4 - W4 - S4] = (float4){0.f, 0.f, 0.f, 0.f};
        }
    }
}

// ---------------------------------------------------------------------------
// Kernel 1: QKV GEMM, bf16 MFMA, fused l2norm+scale, REGISTER PREFETCH.
//   BM=128, BN=64 (=1 head), BK=64; next iter's A (4 chunks) + B (2 chunks)
//   loaded during current compute -> no exposed vmem latency at barriers.
// ---------------------------------------------------------------------------
__global__ __launch_bounds__(256) void qkv_mfma(
    const bf16* __restrict__ A, const bf16* __restrict__ W,
    const float* __restrict__ bias, const float* __restrict__ sml,
    bf16* __restrict__ qb, bf16* __restrict__ kb, bf16* __restrict__ vtb)
{
    __shared__ __align__(16) bf16 As[128][72];
    __shared__ __align__(16) bf16 Bs[64][72];

    const int t    = threadIdx.x;
    const int w    = t >> 6;
    const int lane = t & 63;
    const int quad = lane >> 4;
    const int c    = lane & 15;
    const int m0   = blockIdx.x * 128;
    const int n0   = blockIdx.y * 64;

    const int r0 = t >> 3;          // base row 0..31
    const int cg = (t & 7) * 8;     // column offset (same for all chunks)

    f32x4 acc[2][4];
    #pragma unroll
    for (int mt = 0; mt < 2; ++mt)
        #pragma unroll
        for (int nt = 0; nt < 4; ++nt) acc[mt][nt] = (f32x4){0.f,0.f,0.f,0.f};

    // prefetch iteration 0
    bf16x8 areg[4], breg[2];
    #pragma unroll
    for (int p = 0; p < 4; ++p)
        areg[p] = *(const bf16x8*)&A[(size_t)(m0 + r0 + 32 * p) * C_ + cg];
    #pragma unroll
    for (int p = 0; p < 2; ++p)
        breg[p] = *(const bf16x8*)&W[(size_t)(n0 + r0 + 32 * p) * C_ + cg];

    for (int kt = 0; kt < C_; kt += 64) {
        __syncthreads();   // prev iter's LDS reads complete
        #pragma unroll
        for (int p = 0; p < 4; ++p) *(bf16x8*)&As[r0 + 32 * p][cg] = areg[p];
        #pragma unroll
        for (int p = 0; p < 2; ++p) *(bf16x8*)&Bs[r0 + 32 * p][cg] = breg[p];

        const int kt2 = kt + 64;
        if (kt2 < C_) {
            #pragma unroll
            for (int p = 0; p < 4; ++p)
                areg[p] = *(const bf16x8*)&A[(size_t)(m0 + r0 + 32 * p) * C_ + kt2 + cg];
            #pragma unroll
            for (int p = 0; p < 2; ++p)
                breg[p] = *(const bf16x8*)&W[(size_t)(n0 + r0 + 32 * p) * C_ + kt2 + cg];
        }
        __syncthreads();

        #pragma unroll
        for (int ks = 0; ks < 2; ++ks) {
            #pragma unroll
            for (int mt = 0; mt < 2; ++mt) {
                const bf16x8 a = *(const bf16x8*)&As[w * 32 + mt * 16 + c][ks * 32 + quad * 8];
                #pragma unroll
                for (int nt = 0; nt < 4; ++nt) {
                    const bf16x8 b = *(const bf16x8*)&Bs[nt * 16 + c][ks * 32 + quad * 8];
                    acc[mt][nt] = __builtin_amdgcn_mfma_f32_16x16x32_bf16(a, b, acc[mt][nt], 0, 0, 0);
                }
            }
        }
    }

    const int three = blockIdx.y / H_;
    const int h     = blockIdx.y % H_;
    const int bidx  = m0 >> 11;
    const int l0    = (m0 & (L_ - 1)) + w * 32;

    if (three < 2) {
        bf16* dst = (three == 0) ? qb : kb;
        const float scale = (three == 0) ? expf(fminf(sml[h], MAXLOG)) : 1.0f;
        #pragma unroll
        for (int mt = 0; mt < 2; ++mt) {
            float val[4][4];
            float ss[4] = {0.f, 0.f, 0.f, 0.f};
            #pragma unroll
            for (int nt = 0; nt < 4; ++nt) {
                const float bb = bias[n0 + nt * 16 + c];
                #pragma unroll
                for (int reg = 0; reg < 4; ++reg) {
                    const float v = acc[mt][nt][reg] + bb;
                    val[nt][reg] = v;
                    ss[reg] += v * v;
                }
            }
            #pragma unroll
            for (int reg = 0; reg < 4; ++reg) {
                float s = ss[reg];
                #pragma unroll
                for (int off = 1; off < 16; off <<= 1) s += __shfl_xor(s, off, 16);
                const float inv = scale / fmaxf(sqrtf(s), 1e-12f);
                const int l = l0 + mt * 16 + quad * 4 + reg;
                #pragma unroll
                for (int nt = 0; nt < 4; ++nt)
                    dst[((size_t)(bidx * H_ + h) * L_ + l) * D_ + nt * 16 + c] =
                        (bf16)(val[nt][reg] * inv);
            }
        }
    } else {
        #pragma unroll
        for (int mt = 0; mt < 2; ++mt)
            #pragma unroll
            for (int nt = 0; nt < 4; ++nt) {
                const int d = nt * 16 + c;
                const float bb = bias[n0 + d];
                const int l = l0 + mt * 16 + quad * 4;
                bf16x4 o;
                #pragma unroll
                for (int reg = 0; reg < 4; ++reg) o[reg] = (bf16)(acc[mt][nt][reg] + bb);
                *(bf16x4*)&vtb[((size_t)(bidx * H_ + h) * D_ + d) * L_ + l] = o;
            }
    }
}

// ---------------------------------------------------------------------------
// Kernel 2: flash attention v5 (unchanged R11: BQ=64, 768 blocks, register
// prefetch, Q hoisted, P overlays Q LDS).
// ---------------------------------------------------------------------------
__global__ __launch_bounds__(256) void flash_mfma(
    const bf16* __restrict__ q, const bf16* __restrict__ k,
    const bf16* __restrict__ vt, const float* __restrict__ bias,
    const float* __restrict__ sml,
    bf16* __restrict__ aoh, bf16* __restrict__ aol)
{
    __shared__ __align__(16) bf16 QPs[64][72];
    __shared__ __align__(16) bf16 Ks [64][72];
    __shared__ __align__(16) bf16 Vts[64][72];

    const int t    = threadIdx.x;
    const int w    = t >> 6;
    const int lane = t & 63;
    const int quad = lane >> 4;
    const int c    = lane & 15;
    const int q0   = blockIdx.x * 64;
    const int bh   = blockIdx.y;
    const int h    = bh % H_;
    const int b    = bh / H_;
    const size_t base  = (size_t)bh * L_ * D_;
    const size_t vbase = (size_t)bh * D_ * L_;

    const float FMAX = expf(fminf(sml[h], MAXLOG)) + 8.0f;

    #pragma unroll
    for (int p = 0; p < 2; ++p) {
        const int f = t + p * 256;
        const int r = f >> 3, d0 = (f & 7) * 8;
        *(bf16x8*)&QPs[r][d0] = *(const bf16x8*)&q[base + (size_t)(q0 + r) * D_ + d0];
    }
    __syncthreads();
    bf16x8 Qreg[2];
    Qreg[0] = *(const bf16x8*)&QPs[w * 16 + c][quad * 8];
    Qreg[1] = *(const bf16x8*)&QPs[w * 16 + c][32 + quad * 8];

    const int rbase = q0 + w * 16 + quad * 4;

    const int r0  = t >> 3,         c00 = (t & 7) * 8;
    const int r1  = (t + 256) >> 3, c01 = ((t + 256) & 7) * 8;

    bf16x8 kreg[2], vreg[2];
    float  breg[4][4];
    kreg[0] = *(const bf16x8*)&k [base  + (size_t)r0 * D_ + c00];
    kreg[1] = *(const bf16x8*)&k [base  + (size_t)r1 * D_ + c01];
    vreg[0] = *(const bf16x8*)&vt[vbase + (size_t)r0 * L_ + c00];
    vreg[1] = *(const bf16x8*)&vt[vbase + (size_t)r1 * L_ + c01];
    #pragma unroll
    for (int tile = 0; tile < 4; ++tile)
        #pragma unroll
        for (int reg = 0; reg < 4; ++reg)
            breg[tile][reg] = bias[(size_t)(rbase + reg) * L_ + tile * 16 + c];

    float l_acc[4] = {0.f, 0.f, 0.f, 0.f};
    f32x4 O[4];
    #pragma unroll
    for (int i = 0; i < 4; ++i) O[i] = (f32x4){0.f, 0.f, 0.f, 0.f};

    for (int kt = 0; kt < L_; kt += 64) {
        __syncthreads();

        *(bf16x8*)&Ks [r0][c00] = kreg[0];
        *(bf16x8*)&Ks [r1][c01] = kreg[1];
        *(bf16x8*)&Vts[r0][c00] = vreg[0];
        *(bf16x8*)&Vts[r1][c01] = vreg[1];

        f32x4 S[4];
        #pragma unroll
        for (int tile = 0; tile < 4; ++tile)
            #pragma unroll
            for (int reg = 0; reg < 4; ++reg)
                S[tile][reg] = breg[tile][reg];

        const int kt2 = kt + 64;
        if (kt2 < L_) {
            kreg[0] = *(const bf16x8*)&k [base  + (size_t)(kt2 + r0) * D_ + c00];
            kreg[1] = *(const bf16x8*)&k [base  + (size_t)(kt2 + r1) * D_ + c01];
            vreg[0] = *(const bf16x8*)&vt[vbase + (size_t)r0 * L_ + kt2 + c00];
            vreg[1] = *(const bf16x8*)&vt[vbase + (size_t)r1 * L_ + kt2 + c01];
            #pragma unroll
            for (int tile = 0; tile < 4; ++tile)
                #pragma unroll
                for (int reg = 0; reg < 4; ++reg)
                    breg[tile][reg] = bias[(size_t)(rbase + reg) * L_ + kt2 + tile * 16 + c];
        }
        __syncthreads();

        #pragma unroll
        for (int ks = 0; ks < 2; ++ks) {
            #pragma unroll
            for (int tile = 0; tile < 4; ++tile) {
                const bf16x8 bb = *(const bf16x8*)&Ks[tile * 16 + c][ks * 32 + quad * 8];
                S[tile] = __builtin_amdgcn_mfma_f32_16x16x32_bf16(Qreg[ks], bb, S[tile], 0, 0, 0);
            }
        }

        #pragma unroll
        for (int tile = 0; tile < 4; ++tile)
            #pragma unroll
            for (int reg = 0; reg < 4; ++reg) {
                const float pv = __expf(S[tile][reg] - FMAX);
                l_acc[reg] += pv;
                QPs[w * 16 + quad * 4 + reg][tile * 16 + c] = (bf16)pv;
            }
        __syncthreads();

        #pragma unroll
        for (int ks = 0; ks < 2; ++ks) {
            const bf16x8 a = *(const bf16x8*)&QPs[w * 16 + c][ks * 32 + quad * 8];
            #pragma unroll
            for (int tile = 0; tile < 4; ++tile) {
                const bf16x8 bb = *(const bf16x8*)&Vts[tile * 16 + c][ks * 32 + quad * 8];
                O[tile] = __builtin_amdgcn_mfma_f32_16x16x32_bf16(a, bb, O[tile], 0, 0, 0);
            }
        }
    }

    #pragma unroll
    for (int reg = 0; reg < 4; ++reg) {
        float rs = l_acc[reg];
        #pragma unroll
        for (int off = 1; off < 16; off <<= 1) rs += __shfl_xor(rs, off, 16);
        const float linv = 1.0f / rs;
        const int   row  = q0 + w * 16 + quad * 4 + reg;
        const size_t o   = ((size_t)(b * L_ + row)) * C_ + h * 64 + c;
        #pragma unroll
        for (int tile = 0; tile < 4; ++tile) {
            const float v  = O[tile][reg] * linv;
            const bf16  hv = (bf16)v;
            aoh[o + tile * 16] = hv;
            aol[o + tile * 16] = (bf16)(v - (float)hv);
        }
    }
}

// ---------------------------------------------------------------------------
// Kernel 3: projection GEMM, hi/lo-split bf16 MFMA, pre-split inputs,
//   BM=64 (768 blocks @ 3/CU even balance) + REGISTER PREFETCH.
// ---------------------------------------------------------------------------
__global__ __launch_bounds__(256) void proj_mfma(
    const bf16* __restrict__ Ahg, const bf16* __restrict__ Alg,
    const bf16* __restrict__ Whg, const bf16* __restrict__ Wlg,
    const float* __restrict__ bias, float* __restrict__ outp)
{
    __shared__ __align__(16) bf16 Ah[64][72];
    __shared__ __align__(16) bf16 Al[64][72];
    __shared__ __align__(16) bf16 Bh[64][72];
    __shared__ __align__(16) bf16 Bl[64][72];

    const int t    = threadIdx.x;
    const int w    = t >> 6;
    const int lane = t & 63;
    const int quad = lane >> 4;
    const int c    = lane & 15;
    const int m0   = blockIdx.x * 64;
    const int n0   = blockIdx.y * 64;

    const int r0 = t >> 3;          // 0..31
    const int cg = (t & 7) * 8;

    f32x4 acc[4];
    #pragma unroll
    for (int nt = 0; nt < 4; ++nt) acc[nt] = (f32x4){0.f,0.f,0.f,0.f};

    // prefetch iteration 0
    bf16x8 ahreg[2], alreg[2], bhreg[2], blreg[2];
    #pragma unroll
    for (int p = 0; p < 2; ++p) {
        ahreg[p] = *(const bf16x8*)&Ahg[(size_t)(m0 + r0 + 32 * p) * C_ + cg];
        alreg[p] = *(const bf16x8*)&Alg[(size_t)(m0 + r0 + 32 * p) * C_ + cg];
        bhreg[p] = *(const bf16x8*)&Whg[(size_t)(n0 + r0 + 32 * p) * C_ + cg];
        blreg[p] = *(const bf16x8*)&Wlg[(size_t)(n0 + r0 + 32 * p) * C_ + cg];
    }

    for (int kt = 0; kt < C_; kt += 64) {
        __syncthreads();
        #pragma unroll
        for (int p = 0; p < 2; ++p) {
            *(bf16x8*)&Ah[r0 + 32 * p][cg] = ahreg[p];
            *(bf16x8*)&Al[r0 + 32 * p][cg] = alreg[p];
            *(bf16x8*)&Bh[r0 + 32 * p][cg] = bhreg[p];
            *(bf16x8*)&Bl[r0 + 32 * p][cg] = blreg[p];
        }

        const int kt2 = kt + 64;
        if (kt2 < C_) {
            #pragma unroll
            for (int p = 0; p < 2; ++p) {
                ahreg[p] = *(const bf16x8*)&Ahg[(size_t)(m0 + r0 + 32 * p) * C_ + kt2 + cg];
                alreg[p] = *(const bf16x8*)&Alg[(size_t)(m0 + r0 + 32 * p) * C_ + kt2 + cg];
                bhreg[p] = *(const bf16x8*)&Whg[(size_t)(n0 + r0 + 32 * p) * C_ + kt2 + cg];
                blreg[p] = *(const bf16x8*)&Wlg[(size_t)(n0 + r0 + 32 * p) * C_ + kt2 + cg];
            }
        }
        __syncthreads();

        #pragma unroll
        for (int ks = 0; ks < 2; ++ks) {
            const bf16x8 ah = *(const bf16x8*)&Ah[w * 16 + c][ks * 32 + quad * 8];
            const bf16x8 al = *(const bf16x8*)&Al[w * 16 + c][ks * 32 + quad * 8];
            #pragma unroll
            for (int nt = 0; nt < 4; ++nt) {
                const bf16x8 bh = *(const bf16x8*)&Bh[nt * 16 + c][ks * 32 + quad * 8];
                const bf16x8 bl = *(const bf16x8*)&Bl[nt * 16 + c][ks * 32 + quad * 8];
                acc[nt] = __builtin_amdgcn_mfma_f32_16x16x32_bf16(ah, bh, acc[nt], 0, 0, 0);
                acc[nt] = __builtin_amdgcn_mfma_f32_16x16x32_bf16(ah, bl, acc[nt], 0, 0, 0);
                acc[nt] = __builtin_amdgcn_mfma_f32_16x16x32_bf16(al, bh, acc[nt], 0, 0, 0);
            }
        }
    }

    #pragma unroll
    for (int nt = 0; nt < 4; ++nt) {
        const int col = n0 + nt * 16 + c;
        const float bb = bias[col];
        #pragma unroll
        for (int reg = 0; reg < 4; ++reg) {
            const int row = m0 + w * 16 + quad * 4 + reg;
            outp[(size_t)row * C_ + col] = acc[nt][reg] + bb;
        }
    }
}

// ---------------------------------------------------------------------------
extern "C" void kernel_launch(void* const* d_in, const int* in_sizes, int n_in,
                              void* d_out, int out_size, void* d_ws, size_t ws_size,
                              hipStream_t stream)
{
    const float* x         = (const float*)d_in[0];
    const float* attn_bias = (const float*)d_in[1];
    const float* W_qkv     = (const float*)d_in[2];
    const float* b_qkv     = (const float*)d_in[3];
    const float* sml       = (const float*)d_in[4];
    const float* W_proj    = (const float*)d_in[5];
    const float* b_proj    = (const float*)d_in[6];
    float* out = (float*)d_out;

    // ws layout (bf16 elements): qb,kb,vtb | aoh,aol | Wh,Wl | xb | wqb
    bf16* qb  = (bf16*)d_ws;
    bf16* kb  = qb  + SZ_;
    bf16* vtb = kb  + SZ_;
    bf16* aoh = vtb + SZ_;
    bf16* aol = aoh + MC_;
    bf16* Wh  = aol + MC_;
    bf16* Wl  = Wh  + WP_;
    bf16* xb  = Wl  + WP_;
    bf16* wqb = xb  + MC_;

    // 0) fused prep: cvt x/W_qkv to bf16, split W_proj, zero qb..aol
    prep<<<2048, 256, 0, stream>>>(
        (const float4*)x, (const float4*)W_qkv, (const float4*)W_proj,
        xb, wqb, Wh, Wl, (float4*)qb);

    // 1) QKV GEMM (bf16 MFMA, fused l2norm+scale, prefetch)
    qkv_mfma<<<dim3(M_ / 128, (3 * C_) / 64), 256, 0, stream>>>(
        xb, wqb, b_qkv, sml, qb, kb, vtb);

    // 2) flash attention v5 (BQ=64, 768 blocks, register prefetch)
    flash_mfma<<<dim3(L_ / 64, B_ * H_), 256, 0, stream>>>(
        qb, kb, vtb, attn_bias, sml, aoh, aol);

    // 3) projection GEMM (hi/lo split MFMA, BM=64, 768 blocks, prefetch)
    proj_mfma<<<dim3(M_ / 64, C_ / 64), 256, 0, stream>>>(
        aoh, aol, Wh, Wl, b_proj, out);
}